// Round 6
// baseline (577.287 us; speedup 1.0000x reference)
//
#include <hip/hip_runtime.h>
#include <hip/hip_bf16.h>
#include <math.h>

// Problem constants
#define B_SZ   1024
#define D_SZ   512
#define KC_SZ  256
#define NLOW   130816            // 512*511/2

// B pages: per class, 20 K-step pages of 16 KB, per-wave MFMA fragment order:
// line = ((wng*4+ni)*2+h)*64 + lane, lane = q*16+c,
// value[j] = L[d][e], e = wng*64+ni*16+c, d_local = h*32+q*8+j.
#define STEP_ELEMS  8192
#define NSTEPS      20           // 8+6+4+2 triangular 64-K steps
#define CLASS_ELEMS (NSTEPS * STEP_ELEMS)   // 320 KB/class

// Workspace layout (bytes)
#define OFF_XP     (size_t)(KC_SZ * CLASS_ELEMS * 2)          // 80 MiB
#define OFF_TPART  (OFF_XP + 64 * STEP_ELEMS * 2)             // +1 MiB
#define WS_NEED    (OFF_TPART + (size_t)KC_SZ * 8 * 512 * 4)  // +4 MiB

typedef __attribute__((ext_vector_type(4))) float  f32x4;
typedef __attribute__((ext_vector_type(8))) __bf16 bf16x8;

__device__ __forceinline__ int sbase_of(int ct) { return ct * (9 - ct); }

// ---------------------------------------------------------------------------
// K1a: X pages, bf16, A-fragment order. 64 pages (mt 0..7 x kch 0..7),
// 1024 lines each. One thread per line, 256 blocks for full-chip spread.
// ---------------------------------------------------------------------------
__global__ __launch_bounds__(256)
void prep_x(const float* __restrict__ X, __hip_bfloat16* __restrict__ Xp) {
    const int line = blockIdx.x * 256 + threadIdx.x;   // 0..65535
    const int pg = line >> 10, ll = line & 1023;
    const int mt = pg >> 3, kch = pg & 7;
    const int wmg = ll >> 9, mi = (ll >> 7) & 3, h = (ll >> 6) & 1;
    const int lane = ll & 63, q = lane >> 4, c = lane & 15;
    const int row = mt * 128 + wmg * 64 + mi * 16 + c;
    const float* src = X + (size_t)row * D_SZ + kch * 64 + h * 32 + q * 8;
    f32x4 v0 = ((const f32x4*)src)[0];
    f32x4 v1 = ((const f32x4*)src)[1];
    bf16x8 p;
    #pragma unroll
    for (int j = 0; j < 4; ++j) { p[j] = (__bf16)v0[j]; p[j + 4] = (__bf16)v1[j]; }
    *(bf16x8*)((__bf16*)Xp + (size_t)line * 8) = p;
}

// ---------------------------------------------------------------------------
// K1b: B pages (fragment order) + t-partials (t_k = w_k^T L_k, fp32).
// One block per (class, d-tile dt); loops et = 0..dt|1 with register
// prefetch of the next tile's gather across the current barrier/transpose.
// ---------------------------------------------------------------------------
__global__ __launch_bounds__(256)
void prep_b(const float* __restrict__ Ldiag,
            const float* __restrict__ Llow,
            const float* __restrict__ W,
            __hip_bfloat16* __restrict__ Bp,
            float* __restrict__ tpart) {
    __shared__ float Ls[64][65];   // [d_local][e_local]
    __shared__ float Wsm[64];
    __shared__ float pt[4][64];

    const int bid = blockIdx.x;          // kc*8 + dt
    const int kc  = bid >> 3;
    const int dt  = bid & 7;
    const int d0  = dt << 6;
    const int etmax = dt | 1;
    const int tid = threadIdx.x;

    if (tid < 64) Wsm[tid] = W[(size_t)kc * D_SZ + d0 + tid];

    const float* lowb  = Llow  + (size_t)kc * NLOW;
    const float* diagb = Ldiag + (size_t)kc * D_SZ;
    float* tp = tpart + ((size_t)(kc * 8 + dt)) * 512;
    __bf16* cls = (__bf16*)Bp + (size_t)kc * CLASS_ELEMS;

    // stage-in mapping
    const int r  = tid >> 2;             // d row 0..63
    const int cq = (tid & 3) << 4;       // e col chunk
    const int d  = d0 + r;
    const int tri = (d * (d - 1)) >> 1;
    // stage-out mapping
    const int qp = tid >> 5;             // d-chunk 0..7
    const int ep = tid & 31;             // e-pair 0..31
    const int h  = qp >> 2, q = qp & 3;

    auto gather = [&](int et, float* vv) {
        const int e0 = et << 6;
        if (et < dt) {
            const float* base = lowb + tri + e0 + cq;
            #pragma unroll
            for (int j = 0; j < 16; ++j) vv[j] = base[j];
        } else {  // et == dt: diagonal tile
            #pragma unroll
            for (int j = 0; j < 16; ++j) {
                const int e = e0 + cq + j;
                float v = 0.f;
                if (e < d)       v = lowb[tri + e];
                else if (e == d) { float qd = diagb[d]; v = qd * qd; }
                vv[j] = v;
            }
        }
    };

    float v0[16];
    gather(0, v0);

    for (int et = 0; et <= etmax; ++et) {
        const bool zt = (et > dt);       // zero tile (only et == dt+1, dt even)
        if (!zt) {
            #pragma unroll
            for (int j = 0; j < 16; ++j) Ls[r][cq + j] = v0[j];
        }
        __syncthreads();

        // prefetch next tile's gather (flies across transpose + writes)
        float v1[16];
        const bool pf = (et + 1 <= etmax) && (et + 1 <= dt);
        if (pf) gather(et + 1, v1);

        // page for this (et, dt)
        const int ct = et >> 1;
        const int sp = sbase_of(ct) + (dt - (ct << 1));
        const int el0 = ((et & 1) << 6) + (ep << 1);
        const int line0 = ((((el0 >> 6) * 4 + ((el0 >> 4) & 3)) * 2 + h) * 64)
                          + q * 16 + (el0 & 15);
        __bf16* dst = cls + (size_t)sp * STEP_ELEMS + line0 * 8;

        if (zt) {
            bf16x8 z;
            #pragma unroll
            for (int i = 0; i < 8; ++i) z[i] = (__bf16)0.f;
            *(bf16x8*)dst = z;
            *(bf16x8*)(dst + 8) = z;
            __syncthreads();
            if (tid < 64) tp[et * 64 + tid] = 0.f;
        } else {
            bf16x8 p0, p1;
            #pragma unroll
            for (int j = 0; j < 8; ++j) {
                p0[j] = (__bf16)Ls[qp * 8 + j][ep * 2];
                p1[j] = (__bf16)Ls[qp * 8 + j][ep * 2 + 1];
            }
            *(bf16x8*)dst = p0;
            *(bf16x8*)(dst + 8) = p1;
            // t-partial
            {
                const int part = tid >> 6, ei = tid & 63;
                float sum = 0.f;
                #pragma unroll
                for (int j = 0; j < 16; ++j)
                    sum += Wsm[part * 16 + j] * Ls[part * 16 + j][ei];
                pt[part][ei] = sum;
            }
            __syncthreads();
            if (tid < 64)
                tp[et * 64 + tid] = pt[0][tid] + pt[1][tid] + pt[2][tid] + pt[3][tid];
        }
        #pragma unroll
        for (int j = 0; j < 16; ++j) v0[j] = v1[j];
    }
}

// ---------------------------------------------------------------------------
// K2: main GEMM, barrier-free K-loop. 10 phases of BK=128 (64 MFMA each),
// single-buffer kk-group rotation: after group kk's MFMAs, reload that
// group's fragments for phase p+1 (first reuse 3 groups later).
// Epilogue: rsum += (P - t[e])^2 with t summed from tpart directly.
// ---------------------------------------------------------------------------
__constant__ __device__ const int PH_KCH[10] = {0,2,4,6, 2,4,6, 4,6, 6};

__global__ __launch_bounds__(256, 2)
void gml2_main(const __hip_bfloat16* __restrict__ Xp,
               const __hip_bfloat16* __restrict__ Bp,
               const float* __restrict__ tpart,
               float* __restrict__ Out) {
    __shared__ float osum[2][128];

    const int tid = threadIdx.x;
    const int bx  = blockIdx.x;
    // XCD swizzle: all 8 row-tiles of a class on one XCD -> pages L2-resident
    const int xcd = bx & 7;
    const int g   = bx >> 3;
    const int kc  = xcd * 32 + (g >> 3);
    const int mt  = g & 7;

    const int lane = tid & 63;
    const int wave = tid >> 6;
    const int wmg  = wave & 1;
    const int wng  = wave >> 1;
    const int c    = lane & 15;
    const int q    = lane >> 4;

    const __bf16* pA = (const __bf16*)Xp + (size_t)(mt * 8) * STEP_ELEMS;
    const __bf16* pB = (const __bf16*)Bp + (size_t)kc * CLASS_ELEMS;

    int aoff[4][2], boff[4][2];
    #pragma unroll
    for (int mi = 0; mi < 4; ++mi)
        #pragma unroll
        for (int hh = 0; hh < 2; ++hh)
            aoff[mi][hh] = ((((wmg * 4 + mi) * 2 + hh) * 64) + lane) * 8;
    #pragma unroll
    for (int ni = 0; ni < 4; ++ni)
        #pragma unroll
        for (int hh = 0; hh < 2; ++hh)
            boff[ni][hh] = ((((wng * 4 + ni) * 2 + hh) * 64) + lane) * 8;

    f32x4 acc[4][4];
    #pragma unroll
    for (int mi = 0; mi < 4; ++mi)
        #pragma unroll
        for (int ni = 0; ni < 4; ++ni)
            acc[mi][ni] = (f32x4){0.f, 0.f, 0.f, 0.f};
    float rsum[16];
    #pragma unroll
    for (int i = 0; i < 16; ++i) rsum[i] = 0.f;

    // fragment file: one BK=128 phase = 4 kk-groups x (4 A + 4 B) bf16x8
    bf16x8 FA[4][4], FB[4][4];   // [mi|ni][kk]

    // fold ct: subtract t (summed from partials) and square-accumulate.
    auto fold = [&](int ct) {
        float tv_[4];
        #pragma unroll
        for (int ni = 0; ni < 4; ++ni) {
            const int e = ct * 128 + wng * 64 + ni * 16 + c;
            float s_ = 0.f;
            for (int dtv = ct << 1; dtv < 8; ++dtv)
                s_ += tpart[((size_t)(kc * 8 + dtv)) * 512 + e];
            tv_[ni] = s_;
        }
        #pragma unroll
        for (int mi = 0; mi < 4; ++mi)
            #pragma unroll
            for (int ni = 0; ni < 4; ++ni)
                #pragma unroll
                for (int rr = 0; rr < 4; ++rr) {
                    float y_ = acc[mi][ni][rr] - tv_[ni];
                    rsum[mi * 4 + rr] += y_ * y_;
                    acc[mi][ni][rr] = 0.f;
                }
    };

    // preload phase 0 (kch 0, pages 0..1)
    #pragma unroll
    for (int kk = 0; kk < 4; ++kk) {
        const __bf16* pa = pA + (0 + (kk >> 1)) * STEP_ELEMS;
        const __bf16* pb = pB + (0 + (kk >> 1)) * STEP_ELEMS;
        #pragma unroll
        for (int mi = 0; mi < 4; ++mi) FA[mi][kk] = *(const bf16x8*)(pa + aoff[mi][kk & 1]);
        #pragma unroll
        for (int ni = 0; ni < 4; ++ni) FB[ni][kk] = *(const bf16x8*)(pb + boff[ni][kk & 1]);
    }

    #pragma unroll
    for (int p = 0; p < 10; ++p) {
        #pragma unroll
        for (int kk = 0; kk < 4; ++kk) {
            // 16 MFMA, all-independent accumulators
            #pragma unroll
            for (int mi = 0; mi < 4; ++mi)
                #pragma unroll
                for (int ni = 0; ni < 4; ++ni)
                    acc[mi][ni] = __builtin_amdgcn_mfma_f32_16x16x32_bf16(
                        FA[mi][kk], FB[ni][kk], acc[mi][ni], 0, 0, 0);
            // rotate: reload this kk-group for phase p+1
            if (p + 1 < 10) {
                const __bf16* pa = pA + (PH_KCH[p + 1] + (kk >> 1)) * STEP_ELEMS;
                const __bf16* pb = pB + (2 * (p + 1) + (kk >> 1)) * STEP_ELEMS;
                #pragma unroll
                for (int mi = 0; mi < 4; ++mi)
                    FA[mi][kk] = *(const bf16x8*)(pa + aoff[mi][kk & 1]);
                #pragma unroll
                for (int ni = 0; ni < 4; ++ni)
                    FB[ni][kk] = *(const bf16x8*)(pb + boff[ni][kk & 1]);
            }
        }
        if (p == 3)      fold(0);
        else if (p == 6) fold(1);
        else if (p == 8) fold(2);
        else if (p == 9) fold(3);
    }

    // reduce the 16 e-lanes of each quad
    #pragma unroll
    for (int i = 0; i < 16; ++i) {
        float v = rsum[i];
        v += __shfl_xor(v, 1, 64);
        v += __shfl_xor(v, 2, 64);
        v += __shfl_xor(v, 4, 64);
        v += __shfl_xor(v, 8, 64);
        rsum[i] = v;
    }
    if (c == 0) {
        #pragma unroll
        for (int mi = 0; mi < 4; ++mi)
            #pragma unroll
            for (int rr = 0; rr < 4; ++rr)
                osum[wng][wmg * 64 + mi * 16 + q * 4 + rr] = rsum[mi * 4 + rr];
    }
    __syncthreads();
    if (tid < 128) {
        float v = osum[0][tid] + osum[1][tid];
        Out[(size_t)(mt * 128 + tid) * KC_SZ + kc] = sqrtf(v);
    }
}

// ---------------------------------------------------------------------------
// Fallback (round-2 kernel, proven, ws-independent).
// ---------------------------------------------------------------------------
#define FLDA 40
#define BM 128
#define BN 128
__device__ __forceinline__ void fstep_map(int s, int& ct, int& k0) {
    if (s < 16)      { ct = 0; k0 = s * 32; }
    else if (s < 28) { ct = 1; k0 = 128 + (s - 16) * 32; }
    else if (s < 36) { ct = 2; k0 = 256 + (s - 28) * 32; }
    else             { ct = 3; k0 = 384 + (s - 36) * 32; }
}
__global__ __launch_bounds__(256, 2)
void gml2_fallback(const float* __restrict__ X, const float* __restrict__ W,
                   const float* __restrict__ Ldiag, const float* __restrict__ Llow,
                   float* __restrict__ Out) {
    __shared__ __bf16 As[BM * FLDA];
    __shared__ __bf16 Bs[BN * FLDA];
    __shared__ float  Ws[D_SZ];
    __shared__ float  osum[2][BM];
    const int tid = threadIdx.x;
    const int bx  = blockIdx.x;
    const int xcd = bx & 7;
    const int g   = bx >> 3;
    const int kc  = xcd * 32 + (g >> 3);
    const int mt  = g & 7;
    const int lane = tid & 63, wave = tid >> 6;
    const int wm = (wave & 1) * 64, wn = (wave >> 1) * 64;
    const int c = lane & 15, q = lane >> 4;
    const int am = tid >> 1, akh = (tid & 1) << 4;
    const float* xrow = X + (size_t)(mt * BM + am) * D_SZ;
    const float* wrow = W + (size_t)kc * D_SZ;
    const int be = tid & 127, bd = (tid >> 7) << 4;
    const float* lowbase  = Llow  + (size_t)kc * NLOW;
    const float* diagbase = Ldiag + (size_t)kc * D_SZ;
    if (tid < 128) ((f32x4*)Ws)[tid] = ((const f32x4*)wrow)[tid];
    float rsum[16];
    #pragma unroll
    for (int i = 0; i < 16; ++i) rsum[i] = 0.f;
    f32x4 acc[4][4];
    #pragma unroll
    for (int mi = 0; mi < 4; ++mi)
        #pragma unroll
        for (int ni = 0; ni < 4; ++ni) acc[mi][ni] = (f32x4){0.f, 0.f, 0.f, 0.f};
    f32x4 xr[4];
    float bb[16];
    auto prefetch = [&](int s) {
        int pct, pk0; fstep_map(s, pct, pk0);
        const int pe0 = pct * BN;
        const float* xp = xrow + pk0 + akh;
        #pragma unroll
        for (int i = 0; i < 4; ++i) xr[i] = ((const f32x4*)xp)[i];
        const int e = pe0 + be, d0 = pk0 + bd;
        int tri = (d0 * (d0 - 1)) >> 1;
        if (pk0 >= pe0 + BN) {
            #pragma unroll
            for (int j = 0; j < 16; ++j) { bb[j] = lowbase[tri + e]; tri += d0 + j; }
        } else {
            #pragma unroll
            for (int j = 0; j < 16; ++j) {
                const int d = d0 + j;
                float val = 0.f;
                if (d > e)       val = lowbase[tri + e];
                else if (d == e) { float dq = diagbase[d]; val = dq * dq; }
                bb[j] = val; tri += d;
            }
        }
    };
    prefetch(0);
    __syncthreads();
    int cur_ct = 0;
    for (int s = 0; s < 40; ++s) {
        int ct, k0; fstep_map(s, ct, k0);
        if (ct != cur_ct) {
            #pragma unroll
            for (int mi = 0; mi < 4; ++mi)
                #pragma unroll
                for (int ni = 0; ni < 4; ++ni)
                    #pragma unroll
                    for (int r = 0; r < 4; ++r) {
                        float y = acc[mi][ni][r];
                        rsum[mi * 4 + r] += y * y;
                        acc[mi][ni][r] = 0.f;
                    }
            cur_ct = ct;
        }
        bf16x8 ap0, ap1;
        {
            const f32x4* wsp = (const f32x4*)&Ws[k0 + akh];
            #pragma unroll
            for (int i = 0; i < 4; ++i) {
                f32x4 wv = wsp[i];
                #pragma unroll
                for (int l = 0; l < 4; ++l) {
                    float v = xr[i][l] - wv[l];
                    int idx = i * 4 + l;
                    if (idx < 8) ap0[idx] = (__bf16)v;
                    else         ap1[idx - 8] = (__bf16)v;
                }
            }
        }
        bf16x8 bp0, bp1;
        #pragma unroll
        for (int j = 0; j < 8; ++j) { bp0[j] = (__bf16)bb[j]; bp1[j] = (__bf16)bb[j + 8]; }
        __syncthreads();
        *(bf16x8*)&As[am * FLDA + akh]     = ap0;
        *(bf16x8*)&As[am * FLDA + akh + 8] = ap1;
        *(bf16x8*)&Bs[be * FLDA + bd]      = bp0;
        *(bf16x8*)&Bs[be * FLDA + bd + 8]  = bp1;
        if (s + 1 < 40) prefetch(s + 1);
        __syncthreads();
        bf16x8 af[4], bfr[4];
        #pragma unroll
        for (int mi = 0; mi < 4; ++mi)
            af[mi] = *(const bf16x8*)&As[(wm + mi * 16 + c) * FLDA + q * 8];
        #pragma unroll
        for (int ni = 0; ni < 4; ++ni)
            bfr[ni] = *(const bf16x8*)&Bs[(wn + ni * 16 + c) * FLDA + q * 8];
        #pragma unroll
        for (int mi = 0; mi < 4; ++mi)
            #pragma unroll
            for (int ni = 0; ni < 4; ++ni)
                acc[mi][ni] = __builtin_amdgcn_mfma_f32_16x16x32_bf16(
                    af[mi], bfr[ni], acc[mi][ni], 0, 0, 0);
    }
    #pragma unroll
    for (int mi = 0; mi < 4; ++mi)
        #pragma unroll
        for (int ni = 0; ni < 4; ++ni)
            #pragma unroll
            for (int r = 0; r < 4; ++r) {
                float y = acc[mi][ni][r];
                rsum[mi * 4 + r] += y * y;
            }
    #pragma unroll
    for (int i = 0; i < 16; ++i) {
        float s = rsum[i];
        s += __shfl_xor(s, 1, 64);
        s += __shfl_xor(s, 2, 64);
        s += __shfl_xor(s, 4, 64);
        s += __shfl_xor(s, 8, 64);
        rsum[i] = s;
    }
    const int wnIdx = wave >> 1;
    if (c == 0) {
        #pragma unroll
        for (int mi = 0; mi < 4; ++mi)
            #pragma unroll
            for (int r = 0; r < 4; ++r)
                osum[wnIdx][wm + mi * 16 + q * 4 + r] = rsum[mi * 4 + r];
    }
    __syncthreads();
    if (tid < BM) {
        float s = osum[0][tid] + osum[1][tid];
        Out[(size_t)(mt * BM + tid) * KC_SZ + kc] = sqrtf(s);
    }
}

extern "C" void kernel_launch(void* const* d_in, const int* in_sizes, int n_in,
                              void* d_out, int out_size, void* d_ws, size_t ws_size,
                              hipStream_t stream) {
    const float* X  = (const float*)d_in[0];   // [1024, 512]
    const float* W  = (const float*)d_in[1];   // [256, 1, 512]
    const float* Ld = (const float*)d_in[2];   // [256, 512]
    const float* Ll = (const float*)d_in[3];   // [256, 130816]
    float* Out = (float*)d_out;                // [1024, 256]

    if (ws_size >= WS_NEED) {
        __hip_bfloat16* Bp    = (__hip_bfloat16*)d_ws;
        __hip_bfloat16* Xp    = (__hip_bfloat16*)((char*)d_ws + OFF_XP);
        float*          tpart = (float*)((char*)d_ws + OFF_TPART);
        prep_x  <<<dim3(256),         dim3(256), 0, stream>>>(X, Xp);
        prep_b  <<<dim3(KC_SZ * 8),   dim3(256), 0, stream>>>(Ld, Ll, W, Bp, tpart);
        gml2_main<<<dim3(KC_SZ * 8),  dim3(256), 0, stream>>>(Xp, Bp, tpart, Out);
    } else {
        gml2_fallback<<<dim3(KC_SZ * 8), dim3(256), 0, stream>>>(X, W, Ld, Ll, Out);
    }
}

// Round 7
// 366.174 us; speedup vs baseline: 1.5765x; 1.5765x over previous
//
#include <hip/hip_runtime.h>
#include <hip/hip_bf16.h>
#include <math.h>

// Problem constants
#define B_SZ   1024
#define D_SZ   512
#define KC_SZ  256
#define NLOW   130816            // 512*511/2

// Pages: 20 K-step pages of 16 KB per class, per-wave MFMA fragment order:
// line = ((wg*4+i)*2+h)*64 + lane, lane = q*16+c,
// value[j] = elem at (row/col = wg*64+i*16+c, k_local = h*32+q*8+j).
#define STEP_ELEMS  8192
#define NSTEPS      20           // 8+6+4+2 triangular 64-K steps
#define CLASS_ELEMS (NSTEPS * STEP_ELEMS)   // 320 KB/class

// Workspace layout (bytes)
#define OFF_XP     (size_t)(KC_SZ * CLASS_ELEMS * 2)          // 80 MiB
#define OFF_TPART  (OFF_XP + 64 * STEP_ELEMS * 2)             // +1 MiB
#define WS_NEED    (OFF_TPART + (size_t)KC_SZ * 8 * 512 * 4)  // +4 MiB

typedef __attribute__((ext_vector_type(4))) float  f32x4;
typedef __attribute__((ext_vector_type(8))) __bf16 bf16x8;

__device__ __forceinline__ void load_lds_16B(const __bf16* g, __bf16* l) {
    __builtin_amdgcn_global_load_lds(
        (const __attribute__((address_space(1))) unsigned int*)g,
        (__attribute__((address_space(3))) unsigned int*)l, 16, 0, 0);
}

__device__ __forceinline__ int sbase_of(int ct) { return ct * (9 - ct); }
__device__ __forceinline__ int kch_of(int s) {
    return (s < 8) ? s : (s < 14) ? s - 6 : (s < 18) ? s - 10 : s - 12;
}

// ---------------------------------------------------------------------------
// K1a: X pages, bf16, A-fragment order. 64 pages (mt 0..7 x kch 0..7).
// ---------------------------------------------------------------------------
__global__ __launch_bounds__(256)
void prep_x(const float* __restrict__ X, __hip_bfloat16* __restrict__ Xp) {
    const int line = blockIdx.x * 256 + threadIdx.x;   // 0..65535
    const int pg = line >> 10, ll = line & 1023;
    const int mt = pg >> 3, kch = pg & 7;
    const int wmg = ll >> 9, mi = (ll >> 7) & 3, h = (ll >> 6) & 1;
    const int lane = ll & 63, q = lane >> 4, c = lane & 15;
    const int row = mt * 128 + wmg * 64 + mi * 16 + c;
    const float* src = X + (size_t)row * D_SZ + kch * 64 + h * 32 + q * 8;
    f32x4 v0 = ((const f32x4*)src)[0];
    f32x4 v1 = ((const f32x4*)src)[1];
    bf16x8 p;
    #pragma unroll
    for (int j = 0; j < 4; ++j) { p[j] = (__bf16)v0[j]; p[j + 4] = (__bf16)v1[j]; }
    *(bf16x8*)((__bf16*)Xp + (size_t)line * 8) = p;
}

// ---------------------------------------------------------------------------
// K1b: B pages (fragment order) + t-partials (t_k = w_k^T L_k, fp32).
// One block per (class, d-tile dt); pipelined over et tiles.
// ---------------------------------------------------------------------------
__global__ __launch_bounds__(256)
void prep_b(const float* __restrict__ Ldiag,
            const float* __restrict__ Llow,
            const float* __restrict__ W,
            __hip_bfloat16* __restrict__ Bp,
            float* __restrict__ tpart) {
    __shared__ float Ls[64][65];
    __shared__ float Wsm[64];
    __shared__ float pt[4][64];

    const int bid = blockIdx.x;          // kc*8 + dt
    const int kc  = bid >> 3;
    const int dt  = bid & 7;
    const int d0  = dt << 6;
    const int etmax = dt | 1;
    const int tid = threadIdx.x;

    if (tid < 64) Wsm[tid] = W[(size_t)kc * D_SZ + d0 + tid];

    const float* lowb  = Llow  + (size_t)kc * NLOW;
    const float* diagb = Ldiag + (size_t)kc * D_SZ;
    float* tp = tpart + ((size_t)(kc * 8 + dt)) * 512;
    __bf16* cls = (__bf16*)Bp + (size_t)kc * CLASS_ELEMS;

    const int r  = tid >> 2;             // d row 0..63
    const int cq = (tid & 3) << 4;       // e col chunk
    const int d  = d0 + r;
    const int tri = (d * (d - 1)) >> 1;
    const int qp = tid >> 5;             // d-chunk 0..7
    const int ep = tid & 31;             // e-pair 0..31
    const int h  = qp >> 2, q = qp & 3;

    auto gather = [&](int et, float* vv) {
        const int e0 = et << 6;
        if (et < dt) {
            const float* base = lowb + tri + e0 + cq;
            #pragma unroll
            for (int j = 0; j < 16; ++j) vv[j] = base[j];
        } else {  // et == dt: diagonal tile
            #pragma unroll
            for (int j = 0; j < 16; ++j) {
                const int e = e0 + cq + j;
                float v = 0.f;
                if (e < d)       v = lowb[tri + e];
                else if (e == d) { float qd = diagb[d]; v = qd * qd; }
                vv[j] = v;
            }
        }
    };

    float v0[16];
    gather(0, v0);

    for (int et = 0; et <= etmax; ++et) {
        const bool zt = (et > dt);       // zero tile
        if (!zt) {
            #pragma unroll
            for (int j = 0; j < 16; ++j) Ls[r][cq + j] = v0[j];
        }
        __syncthreads();

        float v1[16];
        const bool pf = (et + 1 <= etmax) && (et + 1 <= dt);
        if (pf) gather(et + 1, v1);

        const int ct = et >> 1;
        const int sp = sbase_of(ct) + (dt - (ct << 1));
        const int el0 = ((et & 1) << 6) + (ep << 1);
        const int line0 = ((((el0 >> 6) * 4 + ((el0 >> 4) & 3)) * 2 + h) * 64)
                          + q * 16 + (el0 & 15);
        __bf16* dst = cls + (size_t)sp * STEP_ELEMS + line0 * 8;

        if (zt) {
            bf16x8 z;
            #pragma unroll
            for (int i = 0; i < 8; ++i) z[i] = (__bf16)0.f;
            *(bf16x8*)dst = z;
            *(bf16x8*)(dst + 8) = z;
            __syncthreads();
            if (tid < 64) tp[et * 64 + tid] = 0.f;
        } else {
            bf16x8 p0, p1;
            #pragma unroll
            for (int j = 0; j < 8; ++j) {
                p0[j] = (__bf16)Ls[qp * 8 + j][ep * 2];
                p1[j] = (__bf16)Ls[qp * 8 + j][ep * 2 + 1];
            }
            *(bf16x8*)dst = p0;
            *(bf16x8*)(dst + 8) = p1;
            {
                const int part = tid >> 6, ei = tid & 63;
                float sum = 0.f;
                #pragma unroll
                for (int j = 0; j < 16; ++j)
                    sum += Wsm[part * 16 + j] * Ls[part * 16 + j][ei];
                pt[part][ei] = sum;
            }
            __syncthreads();
            if (tid < 64)
                tp[et * 64 + tid] = pt[0][tid] + pt[1][tid] + pt[2][tid] + pt[3][tid];
        }
        #pragma unroll
        for (int j = 0; j < 16; ++j) v0[j] = v1[j];
    }
}

// ---------------------------------------------------------------------------
// K2: main GEMM. A page via double-buffered LDS DMA (shared by all 4 waves,
// quarters A's L2 traffic); B via 2-deep register rotation (r5-proven, no
// spill). One barrier per 64-K step; DMA issued one step ahead.
// ---------------------------------------------------------------------------
__global__ __launch_bounds__(256, 2)
void gml2_main(const __hip_bfloat16* __restrict__ Xp,
               const __hip_bfloat16* __restrict__ Bp,
               const float* __restrict__ tpart,
               float* __restrict__ Out) {
    __shared__ __bf16 Abuf[2][STEP_ELEMS];   // 2 x 16 KB
    __shared__ float  osum[2][128];

    const int tid = threadIdx.x;
    const int bx  = blockIdx.x;
    // XCD swizzle: all 8 row-tiles of a class on one XCD -> B pages L2-resident
    const int xcd = bx & 7;
    const int g   = bx >> 3;
    const int kc  = xcd * 32 + (g >> 3);
    const int mt  = g & 7;

    const int lane = tid & 63;
    const int wave = tid >> 6;
    const int wmg  = wave & 1;
    const int wng  = wave >> 1;
    const int c    = lane & 15;
    const int q    = lane >> 4;

    const __bf16* pA = (const __bf16*)Xp + (size_t)(mt * 8) * STEP_ELEMS;
    const __bf16* pB = (const __bf16*)Bp + (size_t)kc * CLASS_ELEMS;

    // B fragment element offsets within a page
    int boff[4][2];
    #pragma unroll
    for (int ni = 0; ni < 4; ++ni)
        #pragma unroll
        for (int hh = 0; hh < 2; ++hh)
            boff[ni][hh] = ((((wng * 4 + ni) * 2 + hh) * 64) + lane) * 8;
    // A fragment element offsets within the LDS page (same line layout)
    int aoff[4][2];
    #pragma unroll
    for (int mi = 0; mi < 4; ++mi)
        #pragma unroll
        for (int hh = 0; hh < 2; ++hh)
            aoff[mi][hh] = ((((wmg * 4 + mi) * 2 + hh) * 64) + lane) * 8;

    f32x4 acc[4][4];
    #pragma unroll
    for (int mi = 0; mi < 4; ++mi)
        #pragma unroll
        for (int ni = 0; ni < 4; ++ni)
            acc[mi][ni] = (f32x4){0.f, 0.f, 0.f, 0.f};
    float rsum[16];
    #pragma unroll
    for (int i = 0; i < 16; ++i) rsum[i] = 0.f;

    bf16x8 fb0[4][2], fb1[4][2];

#define DMA_A(KCH, BUF) {                                                      \
    const __bf16* src_ = pA + (KCH) * STEP_ELEMS;                              \
    _Pragma("unroll") for (int i_ = 0; i_ < 4; ++i_) {                         \
        const int off_ = (wave * 4 + i_) * 512 + lane * 8;                     \
        load_lds_16B(src_ + off_, &Abuf[BUF][off_]); } }
#define LOAD_B(FB, SP) { const __bf16* p_ = pB + (SP) * STEP_ELEMS;            \
    _Pragma("unroll") for (int ni = 0; ni < 4; ++ni)                           \
    _Pragma("unroll") for (int hh = 0; hh < 2; ++hh)                           \
        FB[ni][hh] = *(const bf16x8*)(p_ + boff[ni][hh]); }
#define MFMA_STEP(BUF, FB) {                                                   \
    bf16x8 fa_[4][2];                                                          \
    _Pragma("unroll") for (int mi = 0; mi < 4; ++mi)                           \
    _Pragma("unroll") for (int hh = 0; hh < 2; ++hh)                           \
        fa_[mi][hh] = *(const bf16x8*)&Abuf[BUF][aoff[mi][hh]];                \
    _Pragma("unroll") for (int mi = 0; mi < 4; ++mi)                           \
    _Pragma("unroll") for (int ni = 0; ni < 4; ++ni)                           \
    _Pragma("unroll") for (int hh = 0; hh < 2; ++hh)                           \
        acc[mi][ni] = __builtin_amdgcn_mfma_f32_16x16x32_bf16(                 \
            fa_[mi][hh], FB[ni][hh], acc[mi][ni], 0, 0, 0); }

    // fold ct: subtract t (summed from partials) and square-accumulate.
    auto fold = [&](int ct) {
        float tv_[4];
        #pragma unroll
        for (int ni = 0; ni < 4; ++ni) {
            const int e = ct * 128 + wng * 64 + ni * 16 + c;
            float s_ = 0.f;
            for (int dtv = ct << 1; dtv < 8; ++dtv)
                s_ += tpart[((size_t)(kc * 8 + dtv)) * 512 + e];
            tv_[ni] = s_;
        }
        #pragma unroll
        for (int mi = 0; mi < 4; ++mi)
            #pragma unroll
            for (int ni = 0; ni < 4; ++ni)
                #pragma unroll
                for (int rr = 0; rr < 4; ++rr) {
                    float y_ = acc[mi][ni][rr] - tv_[ni];
                    rsum[mi * 4 + rr] += y_ * y_;
                    acc[mi][ni][rr] = 0.f;
                }
    };

    DMA_A(0, 0);
    LOAD_B(fb0, 0);
    __syncthreads();   // vmcnt drain: DMA(0) visible

    for (int s = 0; s < NSTEPS; s += 2) {
        // ---- even step s: A in Abuf[0], B in fb0 ----
        if (s == 8)       fold(0);
        else if (s == 14) fold(1);
        else if (s == 18) fold(2);

        DMA_A(kch_of(s + 1), 1);            // covered by 32 MFMAs below
        if (s + 1 < NSTEPS) LOAD_B(fb1, s + 1);
        MFMA_STEP(0, fb0);
        __syncthreads();                    // DMA(s+1) visible; Abuf[0] free

        // ---- odd step s+1: A in Abuf[1], B in fb1 ----
        if (s + 2 < NSTEPS) {
            DMA_A(kch_of(s + 2), 0);
            LOAD_B(fb0, s + 2);
        }
        MFMA_STEP(1, fb1);
        __syncthreads();                    // DMA(s+2) visible; Abuf[1] free
    }
    fold(3);

    // reduce the 16 e-lanes of each quad
    #pragma unroll
    for (int i = 0; i < 16; ++i) {
        float v = rsum[i];
        v += __shfl_xor(v, 1, 64);
        v += __shfl_xor(v, 2, 64);
        v += __shfl_xor(v, 4, 64);
        v += __shfl_xor(v, 8, 64);
        rsum[i] = v;
    }
    if (c == 0) {
        #pragma unroll
        for (int mi = 0; mi < 4; ++mi)
            #pragma unroll
            for (int rr = 0; rr < 4; ++rr)
                osum[wng][wmg * 64 + mi * 16 + q * 4 + rr] = rsum[mi * 4 + rr];
    }
    __syncthreads();
    if (tid < 128) {
        float v = osum[0][tid] + osum[1][tid];
        Out[(size_t)(mt * 128 + tid) * KC_SZ + kc] = sqrtf(v);
    }
}

// ---------------------------------------------------------------------------
// Fallback (round-2 kernel, proven, ws-independent).
// ---------------------------------------------------------------------------
#define FLDA 40
#define BM 128
#define BN 128
__device__ __forceinline__ void fstep_map(int s, int& ct, int& k0) {
    if (s < 16)      { ct = 0; k0 = s * 32; }
    else if (s < 28) { ct = 1; k0 = 128 + (s - 16) * 32; }
    else if (s < 36) { ct = 2; k0 = 256 + (s - 28) * 32; }
    else             { ct = 3; k0 = 384 + (s - 36) * 32; }
}
__global__ __launch_bounds__(256, 2)
void gml2_fallback(const float* __restrict__ X, const float* __restrict__ W,
                   const float* __restrict__ Ldiag, const float* __restrict__ Llow,
                   float* __restrict__ Out) {
    __shared__ __bf16 As[BM * FLDA];
    __shared__ __bf16 Bs[BN * FLDA];
    __shared__ float  Ws[D_SZ];
    __shared__ float  osum[2][BM];
    const int tid = threadIdx.x;
    const int bx  = blockIdx.x;
    const int xcd = bx & 7;
    const int g   = bx >> 3;
    const int kc  = xcd * 32 + (g >> 3);
    const int mt  = g & 7;
    const int lane = tid & 63, wave = tid >> 6;
    const int wm = (wave & 1) * 64, wn = (wave >> 1) * 64;
    const int c = lane & 15, q = lane >> 4;
    const int am = tid >> 1, akh = (tid & 1) << 4;
    const float* xrow = X + (size_t)(mt * BM + am) * D_SZ;
    const float* wrow = W + (size_t)kc * D_SZ;
    const int be = tid & 127, bd = (tid >> 7) << 4;
    const float* lowbase  = Llow  + (size_t)kc * NLOW;
    const float* diagbase = Ldiag + (size_t)kc * D_SZ;
    if (tid < 128) ((f32x4*)Ws)[tid] = ((const f32x4*)wrow)[tid];
    float rsum[16];
    #pragma unroll
    for (int i = 0; i < 16; ++i) rsum[i] = 0.f;
    f32x4 acc[4][4];
    #pragma unroll
    for (int mi = 0; mi < 4; ++mi)
        #pragma unroll
        for (int ni = 0; ni < 4; ++ni) acc[mi][ni] = (f32x4){0.f, 0.f, 0.f, 0.f};
    f32x4 xr[4];
    float bb[16];
    auto prefetch = [&](int s) {
        int pct, pk0; fstep_map(s, pct, pk0);
        const int pe0 = pct * BN;
        const float* xp = xrow + pk0 + akh;
        #pragma unroll
        for (int i = 0; i < 4; ++i) xr[i] = ((const f32x4*)xp)[i];
        const int e = pe0 + be, d0 = pk0 + bd;
        int tri = (d0 * (d0 - 1)) >> 1;
        if (pk0 >= pe0 + BN) {
            #pragma unroll
            for (int j = 0; j < 16; ++j) { bb[j] = lowbase[tri + e]; tri += d0 + j; }
        } else {
            #pragma unroll
            for (int j = 0; j < 16; ++j) {
                const int d = d0 + j;
                float val = 0.f;
                if (d > e)       val = lowbase[tri + e];
                else if (d == e) { float dq = diagbase[d]; val = dq * dq; }
                bb[j] = val; tri += d;
            }
        }
    };
    prefetch(0);
    __syncthreads();
    int cur_ct = 0;
    for (int s = 0; s < 40; ++s) {
        int ct, k0; fstep_map(s, ct, k0);
        if (ct != cur_ct) {
            #pragma unroll
            for (int mi = 0; mi < 4; ++mi)
                #pragma unroll
                for (int ni = 0; ni < 4; ++ni)
                    #pragma unroll
                    for (int r = 0; r < 4; ++r) {
                        float y = acc[mi][ni][r];
                        rsum[mi * 4 + r] += y * y;
                        acc[mi][ni][r] = 0.f;
                    }
            cur_ct = ct;
        }
        bf16x8 ap0, ap1;
        {
            const f32x4* wsp = (const f32x4*)&Ws[k0 + akh];
            #pragma unroll
            for (int i = 0; i < 4; ++i) {
                f32x4 wv = wsp[i];
                #pragma unroll
                for (int l = 0; l < 4; ++l) {
                    float v = xr[i][l] - wv[l];
                    int idx = i * 4 + l;
                    if (idx < 8) ap0[idx] = (__bf16)v;
                    else         ap1[idx - 8] = (__bf16)v;
                }
            }
        }
        bf16x8 bp0, bp1;
        #pragma unroll
        for (int j = 0; j < 8; ++j) { bp0[j] = (__bf16)bb[j]; bp1[j] = (__bf16)bb[j + 8]; }
        __syncthreads();
        *(bf16x8*)&As[am * FLDA + akh]     = ap0;
        *(bf16x8*)&As[am * FLDA + akh + 8] = ap1;
        *(bf16x8*)&Bs[be * FLDA + bd]      = bp0;
        *(bf16x8*)&Bs[be * FLDA + bd + 8]  = bp1;
        if (s + 1 < 40) prefetch(s + 1);
        __syncthreads();
        bf16x8 af[4], bfr[4];
        #pragma unroll
        for (int mi = 0; mi < 4; ++mi)
            af[mi] = *(const bf16x8*)&As[(wm + mi * 16 + c) * FLDA + q * 8];
        #pragma unroll
        for (int ni = 0; ni < 4; ++ni)
            bfr[ni] = *(const bf16x8*)&Bs[(wn + ni * 16 + c) * FLDA + q * 8];
        #pragma unroll
        for (int mi = 0; mi < 4; ++mi)
            #pragma unroll
            for (int ni = 0; ni < 4; ++ni)
                acc[mi][ni] = __builtin_amdgcn_mfma_f32_16x16x32_bf16(
                    af[mi], bfr[ni], acc[mi][ni], 0, 0, 0);
    }
    #pragma unroll
    for (int mi = 0; mi < 4; ++mi)
        #pragma unroll
        for (int ni = 0; ni < 4; ++ni)
            #pragma unroll
            for (int r = 0; r < 4; ++r) {
                float y = acc[mi][ni][r];
                rsum[mi * 4 + r] += y * y;
            }
    #pragma unroll
    for (int i = 0; i < 16; ++i) {
        float s = rsum[i];
        s += __shfl_xor(s, 1, 64);
        s += __shfl_xor(s, 2, 64);
        s += __shfl_xor(s, 4, 64);
        s += __shfl_xor(s, 8, 64);
        rsum[i] = s;
    }
    const int wnIdx = wave >> 1;
    if (c == 0) {
        #pragma unroll
        for (int mi = 0; mi < 4; ++mi)
            #pragma unroll
            for (int r = 0; r < 4; ++r)
                osum[wnIdx][wm + mi * 16 + q * 4 + r] = rsum[mi * 4 + r];
    }
    __syncthreads();
    if (tid < BM) {
        float s = osum[0][tid] + osum[1][tid];
        Out[(size_t)(mt * BM + tid) * KC_SZ + kc] = sqrtf(s);
    }
}

extern "C" void kernel_launch(void* const* d_in, const int* in_sizes, int n_in,
                              void* d_out, int out_size, void* d_ws, size_t ws_size,
                              hipStream_t stream) {
    const float* X  = (const float*)d_in[0];   // [1024, 512]
    const float* W  = (const float*)d_in[1];   // [256, 1, 512]
    const float* Ld = (const float*)d_in[2];   // [256, 512]
    const float* Ll = (const float*)d_in[3];   // [256, 130816]
    float* Out = (float*)d_out;                // [1024, 256]

    if (ws_size >= WS_NEED) {
        __hip_bfloat16* Bp    = (__hip_bfloat16*)d_ws;
        __hip_bfloat16* Xp    = (__hip_bfloat16*)((char*)d_ws + OFF_XP);
        float*          tpart = (float*)((char*)d_ws + OFF_TPART);
        prep_x  <<<dim3(256),        dim3(256), 0, stream>>>(X, Xp);
        prep_b  <<<dim3(KC_SZ * 8),  dim3(256), 0, stream>>>(Ld, Ll, W, Bp, tpart);
        gml2_main<<<dim3(KC_SZ * 8), dim3(256), 0, stream>>>(Xp, Bp, tpart, Out);
    } else {
        gml2_fallback<<<dim3(KC_SZ * 8), dim3(256), 0, stream>>>(X, W, Ld, Ll, Out);
    }
}